// Round 18
// baseline (244.859 us; speedup 1.0000x reference)
//
#include <hip/hip_runtime.h>
#include <hip/hip_bf16.h>
#include <stdint.h>

typedef unsigned short u16;
typedef unsigned int u32;
typedef __attribute__((ext_vector_type(8))) short bf16x8;
typedef __attribute__((ext_vector_type(4))) float f32x4;
typedef __attribute__((ext_vector_type(2))) u32 u32x2;

__device__ __forceinline__ u16 f2bf(float f) {  // RTNE (fallback path)
  union { float f; u32 u; } x; x.f = f;
  return (u16)((x.u + 0x7FFFu + ((x.u >> 16) & 1u)) >> 16);
}
__device__ __forceinline__ float bf2f(u16 h) {
  union { u32 u; float f; } x; x.u = ((u32)h) << 16; return x.f;
}
__device__ __forceinline__ float bfhi(u32 w) {  // high u16 already in place
  union { u32 u; float f; } x; x.u = w & 0xFFFF0000u; return x.f;
}

// Packed RTNE f32x2 -> 2xbf16 in one u32 (hardware v_cvt_pk_bf16_f32).
__device__ __forceinline__ u32 pkbf(float a, float b) {
  __hip_bfloat162 h = __float22bfloat162_rn(make_float2(a, b));
  union { __hip_bfloat162 h; u32 u; } x; x.h = h; return x.u;
}

// Load 8 consecutive f32, hardware-packed round to bf16.
__device__ __forceinline__ bf16x8 cvt8pk(const float* __restrict__ p) {
  const f32x4 v0 = *(const f32x4*)p;
  const f32x4 v1 = *(const f32x4*)(p + 4);
  union { u32 w[4]; bf16x8 v; } o;
  o.w[0] = pkbf(v0[0], v0[1]);
  o.w[1] = pkbf(v0[2], v0[3]);
  o.w[2] = pkbf(v1[0], v1[1]);
  o.w[3] = pkbf(v1[2], v1[3]);
  return o.v;
}

// Old software-cvt loader (fallback kernel only).
__device__ __forceinline__ bf16x8 cvt8(const float* __restrict__ p) {
  const f32x4 v0 = *(const f32x4*)p;
  const f32x4 v1 = *(const f32x4*)(p + 4);
  bf16x8 o;
#pragma unroll
  for (int j = 0; j < 4; ++j) {
    o[j] = (short)f2bf(v0[j]);
    o[j + 4] = (short)f2bf(v1[j]);
  }
  return o;
}

// One GEMM pass (2 M-subtiles; node kernel + fallback).
__device__ __forceinline__ void gemm_pass(const bf16x8 (&A)[2][4], const u16* Wl,
                                          int lo, int hi, int swb,
                                          f32x4 (&acc)[2][8]) {
  const f32x4 fzero = {0.f, 0.f, 0.f, 0.f};
#pragma unroll
  for (int mt = 0; mt < 2; ++mt)
#pragma unroll
    for (int nt = 0; nt < 8; ++nt) acc[mt][nt] = fzero;
#pragma unroll
  for (int kk = 0; kk < 4; ++kk)
#pragma unroll
    for (int nt = 0; nt < 8; ++nt) {
      const int n = nt * 16 + lo;
      const int b = n * 256 + ((kk * 64 + hi * 16) ^ swb);
      const bf16x8 w = *(const bf16x8*)((const char*)Wl + b);
      acc[0][nt] = __builtin_amdgcn_mfma_f32_16x16x32_bf16(A[0][kk], w, acc[0][nt], 0, 0, 0);
      acc[1][nt] = __builtin_amdgcn_mfma_f32_16x16x32_bf16(A[1][kk], w, acc[1][nt], 0, 0, 0);
    }
}

// ---- 16-row half-tile transpose through a 4 KiB wave-private Z tile ----
// C/D mapping M1 (HW-verified round-5 probe): value r of lane l is
// D[row=(l>>4)*4+r][col=l&15]. Swizzle: byte ^= (row&7)<<4.
__device__ __forceinline__ void zstore_half_pk(const f32x4 (&accm)[8], u16* zw, int lo, int hi) {
#pragma unroll
  for (int r = 0; r < 4; ++r) {
    const int m = hi * 4 + r;            // 0..15
    const int mb = m * 256;
    const int sw = (m & 7) << 4;
#pragma unroll
    for (int np = 0; np < 4; ++np) {     // nt pairs: packed hw cvt
      const u32 w = pkbf(accm[2 * np][r], accm[2 * np + 1][r]);
      const int c0 = (2 * np) * 16 + lo;
      const int c1 = (2 * np + 1) * 16 + lo;
      *(u16*)((char*)zw + (mb + ((c0 * 2) ^ sw))) = (u16)w;
      *(u16*)((char*)zw + (mb + ((c1 * 2) ^ sw))) = (u16)(w >> 16);
    }
  }
}
__device__ __forceinline__ void zload_half(bf16x8 (&A)[4], const u16* zw,
                                           int lo, int hi, int swb) {
  const int mb = lo * 256;               // row = lo, (lo&7) matches swb
#pragma unroll
  for (int kk = 0; kk < 4; ++kk)
    A[kk] = *(const bf16x8*)((const char*)zw + (mb + ((kk * 64 + hi * 16) ^ swb)));
}

// ======= kernel 0: pre-convert + pre-swizzle 6 weight matrices (f32->bf16) ==
__global__ void cvt_wswz_kernel(const float* __restrict__ Wn, const float* __restrict__ We,
                                u16* __restrict__ Wswz) {
  const int t = blockIdx.x * 256 + threadIdx.x;
  if (t >= 12288) return;
  const int mat = t >> 11;               // 0..5 (3x Wn, 3x We)
  const int c = t & 2047;                // chunk within matrix
  const int n = c >> 4, k8 = c & 15;
  const float* __restrict__ src =
      (mat < 3 ? Wn + mat * 16384 : We + (mat - 3) * 16384) + n * 128 + k8 * 8;
  const bf16x8 w = cvt8pk(src);
  const int b = (n * 256 + k8 * 16) ^ ((n & 7) << 4);
  *(bf16x8*)((char*)(Wswz + (size_t)mat * 16384) + b) = w;
}

// ============ kernel 1: Hb[l][n][:] = bf16(X @ Wn[l]^T) ====================
__global__ __launch_bounds__(256, 2) void node_h_kernel(
    const float* __restrict__ X, const u16* __restrict__ Wnswz,
    u16* __restrict__ Hb, int N) {
  __shared__ u16 Wl[128 * 128];   // 32 KiB
  __shared__ u16 Z[4][16 * 128];  // 16 KiB

  const int tid = threadIdx.x;
  const int lane = tid & 63;
  const int wave = tid >> 6;
  const int lo = lane & 15, hi = lane >> 4;
  const int rowbase = blockIdx.x * 128 + wave * 32;
  const int swb = (lo & 7) << 4;

  bf16x8 a[2][4];
#pragma unroll
  for (int mt = 0; mt < 2; ++mt) {
    const int r = rowbase + mt * 16 + lo;
    const float* __restrict__ p = X + (size_t)(r < N ? r : 0) * 128;
#pragma unroll
    for (int kk = 0; kk < 4; ++kk)
      a[mt][kk] = cvt8pk(p + kk * 32 + hi * 8);
  }

  u16* __restrict__ zw = &Z[wave][0];
  f32x4 acc[2][8];

  for (int layer = 0; layer < 3; ++layer) {
#pragma unroll
    for (int i = 0; i < 8; ++i) {  // linear copy of pre-swizzled weights
      const int c = tid + i * 256;
      *(bf16x8*)(Wl + c * 8) = *(const bf16x8*)(Wnswz + layer * 16384 + c * 8);
    }
    __syncthreads();                     // W staged
    gemm_pass(a, Wl, lo, hi, swb, acc);
    __syncthreads();                     // all Wl reads done before next stage

    u16* __restrict__ Ho = Hb + (size_t)layer * N * 128;
#pragma unroll
    for (int mt = 0; mt < 2; ++mt) {
      zstore_half_pk(acc[mt], zw, lo, hi);  // wave-private, in-order DS
      bf16x8 t4[4];
      zload_half(t4, zw, lo, hi, swb);
      const int row = rowbase + mt * 16 + lo;
      if (row < N) {
        u16* __restrict__ o = Ho + (size_t)row * 128;
#pragma unroll
        for (int kk = 0; kk < 4; ++kk)
          *(bf16x8*)(o + kk * 32 + hi * 8) = t4[kk];
      }
    }
  }
}

// ====== kernel 2: persistent 16-edge-wave pass, 14 waves/CU, WIDE gather ====
// 896 thr = 14 waves x 16 edges; Wl 96 KiB + 14 Z tiles 56 KiB = 152 KiB ->
// 1 block/CU, 14 waves. ONE barrier. ALL per-tile gathers (hc+hn+hT) issued
// at the tile top together with the t+1 E/SRC prefetch -> maximal outstanding
// loads per wave. (896,3): 170-reg cap; ledger ~156 -> no spills.
__global__ __launch_bounds__(896, 3) void edge_v18_kernel(
    const float* __restrict__ E, const u32* __restrict__ SRC,
    const u16* __restrict__ Weswz, const u16* __restrict__ Hb,
    float* __restrict__ OUT, int Ne, int N) {
  __shared__ u16 Wl[3 * 16384];    // 96 KiB, all 3 layers
  __shared__ u16 Z[14][16 * 128];  // 56 KiB, wave-private transpose tiles

  const int tid = threadIdx.x;
  const int lane = tid & 63;
  const int wave = tid >> 6;       // 0..13
  const int lo = lane & 15, hi = lane >> 4;
  const int swb = (lo & 7) << 4;
  const f32x4 fzero = {0.f, 0.f, 0.f, 0.f};

  // edge_sources dtype sniff (before barrier; L2-hot).
  bool is64 = true;
#pragma unroll
  for (int t = 1; t < 32; t += 2) is64 = is64 && (SRC[t] == 0u);

  const int stride = (int)gridDim.x * 224;  // 14 waves x 16 edges
  int base = (int)blockIdx.x * 224 + wave * 16;

  // raw SRC for tile 0 (issued before staging barrier)
  u32 rawS;
  {
    const int r0 = base + lo;
    const int c0 = r0 < Ne ? r0 : 0;
    rawS = SRC[is64 ? 2 * c0 : c0];
  }

  // stage all 3 We matrices: 6144 chunks over 896 threads
#pragma unroll
  for (int i = 0; i < 7; ++i) {
    const int c = tid + i * 896;
    if (c < 6144)
      *(bf16x8*)(Wl + c * 8) = *(const bf16x8*)(Weswz + c * 8);
  }
  __syncthreads();  // the ONLY barrier

  // raw E (f32) for tile 0
  f32x4 Epf[4][2];  // [kk][half] — 32 VGPRs, single-buffered
  {
    const int row = base + lo;
    const int rc = row < Ne ? row : 0;
    const float* __restrict__ p = E + (size_t)rc * 128;
#pragma unroll
    for (int kk = 0; kk < 4; ++kk) {
      Epf[kk][0] = *(const f32x4*)(p + kk * 32 + hi * 8);
      Epf[kk][1] = *(const f32x4*)(p + kk * 32 + hi * 8 + 4);
    }
  }

  u16* __restrict__ zw = &Z[wave][0];
  f32x4 acc[8];

  while (true) {
    // ---- consume pipeline state for tile t ----
    int cur = (int)rawS; cur = (cur < 0 || cur >= N) ? 0 : cur;

    bf16x8 a[4];
#pragma unroll
    for (int kk = 0; kk < 4; ++kk) {
      union { u32 w[4]; bf16x8 v; } o;
      o.w[0] = pkbf(Epf[kk][0][0], Epf[kk][0][1]);
      o.w[1] = pkbf(Epf[kk][0][2], Epf[kk][0][3]);
      o.w[2] = pkbf(Epf[kk][1][0], Epf[kk][1][1]);
      o.w[3] = pkbf(Epf[kk][1][2], Epf[kk][1][3]);
      a[kk] = o.v;
    }

    // ---- issue ALL h gathers for tile t up front (hc, hn, hT) ----
    bf16x8 hc[4], hn[4];
    u32x2 hT[8];
    {
      const u16* __restrict__ hp0 = Hb + (size_t)cur * 128;
      const u16* __restrict__ hp1 = Hb + ((size_t)N + cur) * 128;
      const u16* __restrict__ hp2 = Hb + ((size_t)2 * N + cur) * 128;
#pragma unroll
      for (int kk = 0; kk < 4; ++kk) {
        hc[kk] = *(const bf16x8*)(hp0 + kk * 32 + hi * 8);
        hn[kk] = *(const bf16x8*)(hp1 + kk * 32 + hi * 8);
      }
#pragma unroll
      for (int nt = 0; nt < 8; ++nt)
        hT[nt] = *(const u32x2*)(hp2 + nt * 16 + hi * 4);
    }

    // ---- prefetch tile t+1 (clamped; phantom tail hits row 0) ----
    const int nbase = base + stride;
    const bool more = nbase < Ne;
    {
      const int r0 = nbase + lo;
      const int c0 = (r0 < Ne && r0 >= 0) ? r0 : 0;
      rawS = SRC[is64 ? 2 * c0 : c0];
      const int rc = (nbase + lo < Ne && nbase + lo >= 0) ? nbase + lo : 0;
      const float* __restrict__ p = E + (size_t)rc * 128;
#pragma unroll
      for (int kk = 0; kk < 4; ++kk) {
        Epf[kk][0] = *(const f32x4*)(p + kk * 32 + hi * 8);
        Epf[kk][1] = *(const f32x4*)(p + kk * 32 + hi * 8 + 4);
      }
    }

    // ---------------- layer 0 ----------------
#pragma unroll
    for (int nt = 0; nt < 8; ++nt) acc[nt] = fzero;
#pragma unroll
    for (int kk = 0; kk < 4; ++kk)
#pragma unroll
      for (int nt = 0; nt < 8; ++nt) {
        const int n = nt * 16 + lo;
        const int b = n * 256 + ((kk * 64 + hi * 16) ^ swb);
        const bf16x8 w = *(const bf16x8*)((const char*)Wl + b);
        acc[nt] = __builtin_amdgcn_mfma_f32_16x16x32_bf16(a[kk], w, acc[nt], 0, 0, 0);
      }
    zstore_half_pk(acc, zw, lo, hi);
    {
      bf16x8 zl[4];
      zload_half(zl, zw, lo, hi, swb);
#pragma unroll
      for (int kk = 0; kk < 4; ++kk) {
        union { u32 w[4]; bf16x8 v; } o;
#pragma unroll
        for (int jp = 0; jp < 4; ++jp) {
          const float v0 = bf2f((u16)hc[kk][2 * jp]) * bf2f((u16)zl[kk][2 * jp]);
          const float v1 = bf2f((u16)hc[kk][2 * jp + 1]) * bf2f((u16)zl[kk][2 * jp + 1]);
          const float r0 = v0 > 0.f ? v0 : (__expf(v0) - 1.0f);
          const float r1 = v1 > 0.f ? v1 : (__expf(v1) - 1.0f);
          o.w[jp] = pkbf(r0, r1);
        }
        a[kk] = o.v;
      }
    }

    // ---------------- layer 1 ----------------
#pragma unroll
    for (int nt = 0; nt < 8; ++nt) acc[nt] = fzero;
#pragma unroll
    for (int kk = 0; kk < 4; ++kk)
#pragma unroll
      for (int nt = 0; nt < 8; ++nt) {
        const int n = nt * 16 + lo;
        const int b = n * 256 + ((kk * 64 + hi * 16) ^ swb);
        const bf16x8 w = *(const bf16x8*)((const char*)(Wl + 16384) + b);
        acc[nt] = __builtin_amdgcn_mfma_f32_16x16x32_bf16(a[kk], w, acc[nt], 0, 0, 0);
      }
    zstore_half_pk(acc, zw, lo, hi);
    {
      bf16x8 zl[4];
      zload_half(zl, zw, lo, hi, swb);
#pragma unroll
      for (int kk = 0; kk < 4; ++kk) {
        union { u32 w[4]; bf16x8 v; } o;
#pragma unroll
        for (int jp = 0; jp < 4; ++jp) {
          const float v0 = bf2f((u16)hn[kk][2 * jp]) * bf2f((u16)zl[kk][2 * jp]);
          const float v1 = bf2f((u16)hn[kk][2 * jp + 1]) * bf2f((u16)zl[kk][2 * jp + 1]);
          const float r0 = v0 > 0.f ? v0 : (__expf(v0) - 1.0f);
          const float r1 = v1 > 0.f ? v1 : (__expf(v1) - 1.0f);
          o.w[jp] = pkbf(r0, r1);
        }
        a[kk] = o.v;
      }
    }

    // ---------------- layer 2: transposed GEMM D'[feat][edge] ----------------
    {
      const u16* __restrict__ W2 = Wl + 2 * 16384;
      f32x4 accT[8];
#pragma unroll
      for (int nt = 0; nt < 8; ++nt) accT[nt] = fzero;
#pragma unroll
      for (int kk = 0; kk < 4; ++kk)
#pragma unroll
        for (int nt = 0; nt < 8; ++nt) {
          const int n = nt * 16 + lo;
          const int b = n * 256 + ((kk * 64 + hi * 16) ^ swb);
          const bf16x8 w = *(const bf16x8*)((const char*)W2 + b);
          accT[nt] = __builtin_amdgcn_mfma_f32_16x16x32_bf16(w, a[kk], accT[nt], 0, 0, 0);
        }

      // Lane holds D'[f = nt*16 + hi*4 + r][edge = lo].
      const int row = base + lo;
      if (row < Ne) {
        float* __restrict__ op = OUT + (size_t)row * 128;
#pragma unroll
        for (int nt = 0; nt < 8; ++nt) {
          const u32x2 hv = hT[nt];
          f32x4 v;
          const float h0 = bf2f((u16)(hv[0] & 0xFFFFu));
          const float h1 = bfhi(hv[0]);
          const float h2 = bf2f((u16)(hv[1] & 0xFFFFu));
          const float h3 = bfhi(hv[1]);
          const float t0 = h0 * accT[nt][0];
          const float t1 = h1 * accT[nt][1];
          const float t2 = h2 * accT[nt][2];
          const float t3 = h3 * accT[nt][3];
          v[0] = t0 > 0.f ? t0 : (__expf(t0) - 1.0f);
          v[1] = t1 > 0.f ? t1 : (__expf(t1) - 1.0f);
          v[2] = t2 > 0.f ? t2 : (__expf(t2) - 1.0f);
          v[3] = t3 > 0.f ? t3 : (__expf(t3) - 1.0f);
          *(f32x4*)(op + nt * 16 + hi * 4) = v;  // full 64B sector per inst
        }
      }
    }

    if (!more) break;
    base = nbase;
  }
}

// ================= fallback: proven round-6 fused kernel =================
__device__ __forceinline__ void stage_w(const float* __restrict__ Wg, u16* lds, int tid) {
#pragma unroll
  for (int i = 0; i < 8; ++i) {
    const int c = tid + i * 256;
    const int n = c >> 4, k8 = c & 15;
    const bf16x8 w = cvt8(Wg + n * 128 + k8 * 8);
    const int b = (n * 256 + k8 * 16) ^ ((n & 7) << 4);
    *(bf16x8*)((char*)lds + b) = w;
  }
}
__device__ __forceinline__ void combine_store32(const f32x4 (&aH)[2][8], const f32x4 (&aZ)[2][8],
                                                u16* zw, int lo, int hi) {
#pragma unroll
  for (int mt = 0; mt < 2; ++mt)
#pragma unroll
    for (int r = 0; r < 4; ++r)
#pragma unroll
      for (int nt = 0; nt < 8; ++nt) {
        const float v = aH[mt][nt][r] * aZ[mt][nt][r];
        const float e = __expf(v) - 1.0f;
        const u16 o = f2bf(v > 0.f ? v : e);
        const int m = mt * 16 + hi * 4 + r;
        const int c = nt * 16 + lo;
        *(u16*)((char*)zw + ((m * 256) + ((c * 2) ^ ((m & 7) << 4)))) = o;
      }
}
__device__ __forceinline__ void zload32(bf16x8 (&A)[2][4], const u16* zw,
                                        int lo, int hi, int swb) {
#pragma unroll
  for (int mt = 0; mt < 2; ++mt) {
    const int mb = (mt * 16 + lo) * 256;
#pragma unroll
    for (int kk = 0; kk < 4; ++kk)
      A[mt][kk] = *(const bf16x8*)((const char*)zw + (mb + ((kk * 64 + hi * 16) ^ swb)));
  }
}
__global__ __launch_bounds__(256, 2) void edge_fused_f32out_kernel(
    const float* __restrict__ E, const u32* __restrict__ SRC,
    const float* __restrict__ X,
    const float* __restrict__ Wn, const float* __restrict__ We,
    float* __restrict__ OUT, int Ne, int N) {
  __shared__ u16 Wl[128 * 128];
  __shared__ u16 Z[4][32 * 128];
  const int tid = threadIdx.x;
  const int lane = tid & 63;
  const int wave = tid >> 6;
  const int lo = lane & 15, hi = lane >> 4;
  const int rowbase = blockIdx.x * 128 + wave * 32;
  const int swb = (lo & 7) << 4;
  bool is64 = true;
#pragma unroll
  for (int t = 1; t < 32; t += 2) is64 = is64 && (SRC[t] == 0u);
  int row[2];
  bf16x8 a[2][4], xg[2][4];
#pragma unroll
  for (int mt = 0; mt < 2; ++mt) {
    row[mt] = rowbase + mt * 16 + lo;
    const int rc = row[mt] < Ne ? row[mt] : 0;
    int s = (int)SRC[is64 ? (2 * rc) : rc];
    s = (s < 0 || s >= N) ? 0 : s;
    const float* __restrict__ p = E + (size_t)rc * 128;
    const float* __restrict__ px = X + (size_t)s * 128;
#pragma unroll
    for (int kk = 0; kk < 4; ++kk) {
      a[mt][kk] = cvt8(p + kk * 32 + hi * 8);
      xg[mt][kk] = cvt8(px + kk * 32 + hi * 8);
    }
  }
  u16* __restrict__ zw = &Z[wave][0];
  f32x4 accH[2][8], accZ[2][8];
  for (int layer = 0; layer < 3; ++layer) {
    stage_w(Wn + layer * 16384, Wl, tid);
    __syncthreads();
    gemm_pass(xg, Wl, lo, hi, swb, accH);
    __syncthreads();
    stage_w(We + layer * 16384, Wl, tid);
    __syncthreads();
    gemm_pass(a, Wl, lo, hi, swb, accZ);
    __syncthreads();
    if (layer < 2) {
      combine_store32(accH, accZ, zw, lo, hi);
      zload32(a, zw, lo, hi, swb);
    } else {
#pragma unroll
      for (int mt = 0; mt < 2; ++mt)
#pragma unroll
        for (int r = 0; r < 4; ++r) {
          const int grow = rowbase + mt * 16 + hi * 4 + r;
          if (grow < Ne) {
            float* __restrict__ o = OUT + (size_t)grow * 128;
#pragma unroll
            for (int nt = 0; nt < 8; ++nt) {
              const float v = accH[mt][nt][r] * accZ[mt][nt][r];
              const float e = __expf(v) - 1.0f;
              o[nt * 16 + lo] = (v > 0.f ? v : e);
            }
          }
        }
    }
  }
}

extern "C" void kernel_launch(void* const* d_in, const int* in_sizes, int n_in,
                              void* d_out, int out_size, void* d_ws, size_t ws_size,
                              hipStream_t stream) {
  const float* X   = (const float*)d_in[0];  // input       [N][128] f32
  const u32*   SRC = (const u32*)d_in[1];    // edge_sources[Ne] int64/int32
  const float* E   = (const float*)d_in[2];  // e           [Ne][128] f32
  const float* Wn  = (const float*)d_in[3];  // W_node      [3][128][128] f32
  const float* We  = (const float*)d_in[4];  // W_edge      [3][128][128] f32
  float* OUT = (float*)d_out;                // [Ne][128] f32

  const int N  = in_sizes[0] / 128;
  const int Ne = in_sizes[1];

  const size_t hbElems = (size_t)3 * (size_t)N * 128;
  const size_t need = (hbElems + 6 * 16384) * sizeof(u16);  // Hb + 6 swz mats
  if (ws_size >= need) {
    u16* Hb   = (u16*)d_ws;
    u16* Wswz = Hb + hbElems;  // byte offset 768*N -> 16B aligned
    cvt_wswz_kernel<<<48, 256, 0, stream>>>(Wn, We, Wswz);
    node_h_kernel<<<(N + 127) / 128, 256, 0, stream>>>(X, Wswz, Hb, N);
    edge_v18_kernel<<<256, 896, 0, stream>>>(E, SRC, Wswz + 3 * 16384, Hb, OUT, Ne, N);
  } else {
    edge_fused_f32out_kernel<<<(Ne + 127) / 128, 256, 0, stream>>>(E, SRC, X, Wn, We, OUT, Ne, N);
  }
}

// Round 19
// 220.050 us; speedup vs baseline: 1.1127x; 1.1127x over previous
//
#include <hip/hip_runtime.h>
#include <hip/hip_bf16.h>
#include <stdint.h>

typedef unsigned short u16;
typedef unsigned int u32;
typedef __attribute__((ext_vector_type(8))) short bf16x8;
typedef __attribute__((ext_vector_type(4))) float f32x4;
typedef __attribute__((ext_vector_type(2))) u32 u32x2;

__device__ __forceinline__ u16 f2bf(float f) {  // RTNE (fallback path)
  union { float f; u32 u; } x; x.f = f;
  return (u16)((x.u + 0x7FFFu + ((x.u >> 16) & 1u)) >> 16);
}
__device__ __forceinline__ float bf2f(u16 h) {
  union { u32 u; float f; } x; x.u = ((u32)h) << 16; return x.f;
}
__device__ __forceinline__ float bfhi(u32 w) {  // high u16 already in place
  union { u32 u; float f; } x; x.u = w & 0xFFFF0000u; return x.f;
}

// Packed RTNE f32x2 -> 2xbf16 in one u32 (hardware v_cvt_pk_bf16_f32).
__device__ __forceinline__ u32 pkbf(float a, float b) {
  __hip_bfloat162 h = __float22bfloat162_rn(make_float2(a, b));
  union { __hip_bfloat162 h; u32 u; } x; x.h = h; return x.u;
}

// Load 8 consecutive f32, hardware-packed round to bf16.
__device__ __forceinline__ bf16x8 cvt8pk(const float* __restrict__ p) {
  const f32x4 v0 = *(const f32x4*)p;
  const f32x4 v1 = *(const f32x4*)(p + 4);
  union { u32 w[4]; bf16x8 v; } o;
  o.w[0] = pkbf(v0[0], v0[1]);
  o.w[1] = pkbf(v0[2], v0[3]);
  o.w[2] = pkbf(v1[0], v1[1]);
  o.w[3] = pkbf(v1[2], v1[3]);
  return o.v;
}

// Old software-cvt loader (fallback kernel only).
__device__ __forceinline__ bf16x8 cvt8(const float* __restrict__ p) {
  const f32x4 v0 = *(const f32x4*)p;
  const f32x4 v1 = *(const f32x4*)(p + 4);
  bf16x8 o;
#pragma unroll
  for (int j = 0; j < 4; ++j) {
    o[j] = (short)f2bf(v0[j]);
    o[j + 4] = (short)f2bf(v1[j]);
  }
  return o;
}

// One GEMM pass (2 M-subtiles; node kernel + fallback).
__device__ __forceinline__ void gemm_pass(const bf16x8 (&A)[2][4], const u16* Wl,
                                          int lo, int hi, int swb,
                                          f32x4 (&acc)[2][8]) {
  const f32x4 fzero = {0.f, 0.f, 0.f, 0.f};
#pragma unroll
  for (int mt = 0; mt < 2; ++mt)
#pragma unroll
    for (int nt = 0; nt < 8; ++nt) acc[mt][nt] = fzero;
#pragma unroll
  for (int kk = 0; kk < 4; ++kk)
#pragma unroll
    for (int nt = 0; nt < 8; ++nt) {
      const int n = nt * 16 + lo;
      const int b = n * 256 + ((kk * 64 + hi * 16) ^ swb);
      const bf16x8 w = *(const bf16x8*)((const char*)Wl + b);
      acc[0][nt] = __builtin_amdgcn_mfma_f32_16x16x32_bf16(A[0][kk], w, acc[0][nt], 0, 0, 0);
      acc[1][nt] = __builtin_amdgcn_mfma_f32_16x16x32_bf16(A[1][kk], w, acc[1][nt], 0, 0, 0);
    }
}

// ---- 16-row half-tile transpose through a 4 KiB wave-private Z tile ----
// C/D mapping M1 (HW-verified round-5 probe): value r of lane l is
// D[row=(l>>4)*4+r][col=l&15].
// Z-tile swizzle v19: f(row,cb) = cb ^ ((row>>2)<<5) — flips bank bits 3,4
// (disjoint from lo's bank bits 0-2). zstore 2B writes: 32 banks x 2 lanes =
// conflict-free; zload b128 stays 16B-aligned, uniform 8-granule spread.
__device__ __forceinline__ void zstore_half_pk(const f32x4 (&accm)[8], u16* zw, int lo, int hi) {
  const int sw = hi << 5;                // ((m>>2)&3)<<5, m = hi*4+r
#pragma unroll
  for (int r = 0; r < 4; ++r) {
    const int m = hi * 4 + r;            // 0..15
    const int mb = m * 256;
#pragma unroll
    for (int np = 0; np < 4; ++np) {     // nt pairs: packed hw cvt
      const u32 w = pkbf(accm[2 * np][r], accm[2 * np + 1][r]);
      const int c0 = (2 * np) * 16 + lo;
      const int c1 = (2 * np + 1) * 16 + lo;
      *(u16*)((char*)zw + (mb + ((c0 * 2) ^ sw))) = (u16)w;
      *(u16*)((char*)zw + (mb + ((c1 * 2) ^ sw))) = (u16)(w >> 16);
    }
  }
}
__device__ __forceinline__ void zload_half(bf16x8 (&A)[4], const u16* zw,
                                           int lo, int hi, int zsw) {
  const int mb = lo * 256;               // row = lo
#pragma unroll
  for (int kk = 0; kk < 4; ++kk)
    A[kk] = *(const bf16x8*)((const char*)zw + (mb + ((kk * 64 + hi * 16) ^ zsw)));
}

// ======= kernel 0: pre-convert + pre-swizzle 6 weight matrices (f32->bf16) ==
__global__ void cvt_wswz_kernel(const float* __restrict__ Wn, const float* __restrict__ We,
                                u16* __restrict__ Wswz) {
  const int t = blockIdx.x * 256 + threadIdx.x;
  if (t >= 12288) return;
  const int mat = t >> 11;               // 0..5 (3x Wn, 3x We)
  const int c = t & 2047;                // chunk within matrix
  const int n = c >> 4, k8 = c & 15;
  const float* __restrict__ src =
      (mat < 3 ? Wn + mat * 16384 : We + (mat - 3) * 16384) + n * 128 + k8 * 8;
  const bf16x8 w = cvt8pk(src);
  const int b = (n * 256 + k8 * 16) ^ ((n & 7) << 4);
  *(bf16x8*)((char*)(Wswz + (size_t)mat * 16384) + b) = w;
}

// ============ kernel 1: Hb[l][n][:] = bf16(X @ Wn[l]^T) ====================
__global__ __launch_bounds__(256, 2) void node_h_kernel(
    const float* __restrict__ X, const u16* __restrict__ Wnswz,
    u16* __restrict__ Hb, int N) {
  __shared__ u16 Wl[128 * 128];   // 32 KiB
  __shared__ u16 Z[4][16 * 128];  // 16 KiB

  const int tid = threadIdx.x;
  const int lane = tid & 63;
  const int wave = tid >> 6;
  const int lo = lane & 15, hi = lane >> 4;
  const int rowbase = blockIdx.x * 128 + wave * 32;
  const int swb = (lo & 7) << 4;         // weight-LDS swizzle (matches Wswz)
  const int zsw = ((lo >> 2) & 3) << 5;  // Z-tile swizzle (v19)

  bf16x8 a[2][4];
#pragma unroll
  for (int mt = 0; mt < 2; ++mt) {
    const int r = rowbase + mt * 16 + lo;
    const float* __restrict__ p = X + (size_t)(r < N ? r : 0) * 128;
#pragma unroll
    for (int kk = 0; kk < 4; ++kk)
      a[mt][kk] = cvt8pk(p + kk * 32 + hi * 8);
  }

  u16* __restrict__ zw = &Z[wave][0];
  f32x4 acc[2][8];

  for (int layer = 0; layer < 3; ++layer) {
#pragma unroll
    for (int i = 0; i < 8; ++i) {  // linear copy of pre-swizzled weights
      const int c = tid + i * 256;
      *(bf16x8*)(Wl + c * 8) = *(const bf16x8*)(Wnswz + layer * 16384 + c * 8);
    }
    __syncthreads();                     // W staged
    gemm_pass(a, Wl, lo, hi, swb, acc);
    __syncthreads();                     // all Wl reads done before next stage

    u16* __restrict__ Ho = Hb + (size_t)layer * N * 128;
#pragma unroll
    for (int mt = 0; mt < 2; ++mt) {
      zstore_half_pk(acc[mt], zw, lo, hi);  // wave-private, in-order DS
      bf16x8 t4[4];
      zload_half(t4, zw, lo, hi, zsw);
      const int row = rowbase + mt * 16 + lo;
      if (row < N) {
        u16* __restrict__ o = Ho + (size_t)row * 128;
#pragma unroll
        for (int kk = 0; kk < 4; ++kk)
          *(bf16x8*)(o + kk * 32 + hi * 8) = t4[kk];
      }
    }
  }
}

// ====== kernel 2: persistent 16-edge-wave pass (v16 champion + zswizzle) ====
// 768 thr = 12 waves x 16 edges. All 3 We staged once (96 KiB) + 12 private Z
// (48 KiB) = 144 KiB -> 1 block/CU, 12 waves. ONE barrier; after it waves run
// free. Cross-tile E/SRC prefetch + layer-ahead h gathers (deferred schedule —
// proven no-spill at 76 VGPR). Z-tile bank-conflict fix via hi<<5 swizzle.
__global__ __launch_bounds__(768, 3) void edge_v19_kernel(
    const float* __restrict__ E, const u32* __restrict__ SRC,
    const u16* __restrict__ Weswz, const u16* __restrict__ Hb,
    float* __restrict__ OUT, int Ne, int N) {
  __shared__ u16 Wl[3 * 16384];    // 96 KiB, all 3 layers
  __shared__ u16 Z[12][16 * 128];  // 48 KiB, wave-private transpose tiles

  const int tid = threadIdx.x;
  const int lane = tid & 63;
  const int wave = tid >> 6;       // 0..11
  const int lo = lane & 15, hi = lane >> 4;
  const int swb = (lo & 7) << 4;         // weight-LDS swizzle
  const int zsw = ((lo >> 2) & 3) << 5;  // Z-tile swizzle (v19)
  const f32x4 fzero = {0.f, 0.f, 0.f, 0.f};

  // edge_sources dtype sniff (before barrier; L2-hot).
  bool is64 = true;
#pragma unroll
  for (int t = 1; t < 32; t += 2) is64 = is64 && (SRC[t] == 0u);

  const int stride = (int)gridDim.x * 192;
  int base = (int)blockIdx.x * 192 + wave * 16;

  // raw SRC for tile 0 (issued before staging barrier)
  u32 rawS;
  {
    const int r0 = base + lo;
    const int c0 = r0 < Ne ? r0 : 0;
    rawS = SRC[is64 ? 2 * c0 : c0];
  }

  // stage all 3 We matrices: 768 threads x 8 chunks x 16B = 96 KiB
#pragma unroll
  for (int i = 0; i < 8; ++i) {
    const int c = tid + i * 768;
    *(bf16x8*)(Wl + c * 8) = *(const bf16x8*)(Weswz + c * 8);
  }
  __syncthreads();  // the ONLY barrier

  // raw E (f32) for tile 0
  f32x4 Epf[4][2];  // [kk][half] — 32 VGPRs, single-buffered
  {
    const int row = base + lo;
    const int rc = row < Ne ? row : 0;
    const float* __restrict__ p = E + (size_t)rc * 128;
#pragma unroll
    for (int kk = 0; kk < 4; ++kk) {
      Epf[kk][0] = *(const f32x4*)(p + kk * 32 + hi * 8);
      Epf[kk][1] = *(const f32x4*)(p + kk * 32 + hi * 8 + 4);
    }
  }

  u16* __restrict__ zw = &Z[wave][0];
  f32x4 acc[8];

  while (true) {
    // ---- consume pipeline state for tile t ----
    int cur = (int)rawS; cur = (cur < 0 || cur >= N) ? 0 : cur;

    bf16x8 a[4];
#pragma unroll
    for (int kk = 0; kk < 4; ++kk) {
      union { u32 w[4]; bf16x8 v; } o;
      o.w[0] = pkbf(Epf[kk][0][0], Epf[kk][0][1]);
      o.w[1] = pkbf(Epf[kk][0][2], Epf[kk][0][3]);
      o.w[2] = pkbf(Epf[kk][1][0], Epf[kk][1][1]);
      o.w[3] = pkbf(Epf[kk][1][2], Epf[kk][1][3]);
      a[kk] = o.v;
    }

    // issue hc gathers (layer-0 h) for tile t
    bf16x8 hc[4];
    {
      const u16* __restrict__ hp = Hb + (size_t)cur * 128;
#pragma unroll
      for (int kk = 0; kk < 4; ++kk)
        hc[kk] = *(const bf16x8*)(hp + kk * 32 + hi * 8);
    }

    // ---- prefetch tile t+1 (clamped; phantom tail hits row 0) ----
    const int nbase = base + stride;
    const bool more = nbase < Ne;
    {
      const int r0 = nbase + lo;
      const int c0 = (r0 < Ne && r0 >= 0) ? r0 : 0;
      rawS = SRC[is64 ? 2 * c0 : c0];
      const int rc = (nbase + lo < Ne && nbase + lo >= 0) ? nbase + lo : 0;
      const float* __restrict__ p = E + (size_t)rc * 128;
#pragma unroll
      for (int kk = 0; kk < 4; ++kk) {
        Epf[kk][0] = *(const f32x4*)(p + kk * 32 + hi * 8);
        Epf[kk][1] = *(const f32x4*)(p + kk * 32 + hi * 8 + 4);
      }
    }

    // ---------------- layer 0 ----------------
#pragma unroll
    for (int nt = 0; nt < 8; ++nt) acc[nt] = fzero;
#pragma unroll
    for (int kk = 0; kk < 4; ++kk)
#pragma unroll
      for (int nt = 0; nt < 8; ++nt) {
        const int n = nt * 16 + lo;
        const int b = n * 256 + ((kk * 64 + hi * 16) ^ swb);
        const bf16x8 w = *(const bf16x8*)((const char*)Wl + b);
        acc[nt] = __builtin_amdgcn_mfma_f32_16x16x32_bf16(a[kk], w, acc[nt], 0, 0, 0);
      }
    // issue hn (layer-1 h)
    bf16x8 hn[4];
    {
      const u16* __restrict__ hp = Hb + ((size_t)N + cur) * 128;
#pragma unroll
      for (int kk = 0; kk < 4; ++kk)
        hn[kk] = *(const bf16x8*)(hp + kk * 32 + hi * 8);
    }
    zstore_half_pk(acc, zw, lo, hi);
    {
      bf16x8 zl[4];
      zload_half(zl, zw, lo, hi, zsw);
#pragma unroll
      for (int kk = 0; kk < 4; ++kk) {
        union { u32 w[4]; bf16x8 v; } o;
#pragma unroll
        for (int jp = 0; jp < 4; ++jp) {
          const float v0 = bf2f((u16)hc[kk][2 * jp]) * bf2f((u16)zl[kk][2 * jp]);
          const float v1 = bf2f((u16)hc[kk][2 * jp + 1]) * bf2f((u16)zl[kk][2 * jp + 1]);
          const float r0 = v0 > 0.f ? v0 : (__expf(v0) - 1.0f);
          const float r1 = v1 > 0.f ? v1 : (__expf(v1) - 1.0f);
          o.w[jp] = pkbf(r0, r1);
        }
        a[kk] = o.v;
      }
    }

    // ---------------- layer 1 ----------------
#pragma unroll
    for (int nt = 0; nt < 8; ++nt) acc[nt] = fzero;
#pragma unroll
    for (int kk = 0; kk < 4; ++kk)
#pragma unroll
      for (int nt = 0; nt < 8; ++nt) {
        const int n = nt * 16 + lo;
        const int b = n * 256 + ((kk * 64 + hi * 16) ^ swb);
        const bf16x8 w = *(const bf16x8*)((const char*)(Wl + 16384) + b);
        acc[nt] = __builtin_amdgcn_mfma_f32_16x16x32_bf16(a[kk], w, acc[nt], 0, 0, 0);
      }
    // issue hT (layer-2 transposed h slices)
    u32x2 hT[8];
    {
      const u16* __restrict__ hp = Hb + ((size_t)2 * N + cur) * 128;
#pragma unroll
      for (int nt = 0; nt < 8; ++nt)
        hT[nt] = *(const u32x2*)(hp + nt * 16 + hi * 4);
    }
    zstore_half_pk(acc, zw, lo, hi);
    {
      bf16x8 zl[4];
      zload_half(zl, zw, lo, hi, zsw);
#pragma unroll
      for (int kk = 0; kk < 4; ++kk) {
        union { u32 w[4]; bf16x8 v; } o;
#pragma unroll
        for (int jp = 0; jp < 4; ++jp) {
          const float v0 = bf2f((u16)hn[kk][2 * jp]) * bf2f((u16)zl[kk][2 * jp]);
          const float v1 = bf2f((u16)hn[kk][2 * jp + 1]) * bf2f((u16)zl[kk][2 * jp + 1]);
          const float r0 = v0 > 0.f ? v0 : (__expf(v0) - 1.0f);
          const float r1 = v1 > 0.f ? v1 : (__expf(v1) - 1.0f);
          o.w[jp] = pkbf(r0, r1);
        }
        a[kk] = o.v;
      }
    }

    // ---------------- layer 2: transposed GEMM D'[feat][edge] ----------------
    {
      const u16* __restrict__ W2 = Wl + 2 * 16384;
      f32x4 accT[8];
#pragma unroll
      for (int nt = 0; nt < 8; ++nt) accT[nt] = fzero;
#pragma unroll
      for (int kk = 0; kk < 4; ++kk)
#pragma unroll
        for (int nt = 0; nt < 8; ++nt) {
          const int n = nt * 16 + lo;
          const int b = n * 256 + ((kk * 64 + hi * 16) ^ swb);
          const bf16x8 w = *(const bf16x8*)((const char*)W2 + b);
          accT[nt] = __builtin_amdgcn_mfma_f32_16x16x32_bf16(w, a[kk], accT[nt], 0, 0, 0);
        }

      // Lane holds D'[f = nt*16 + hi*4 + r][edge = lo].
      const int row = base + lo;
      if (row < Ne) {
        float* __restrict__ op = OUT + (size_t)row * 128;
#pragma unroll
        for (int nt = 0; nt < 8; ++nt) {
          const u32x2 hv = hT[nt];
          f32x4 v;
          const float h0 = bf2f((u16)(hv[0] & 0xFFFFu));
          const float h1 = bfhi(hv[0]);
          const float h2 = bf2f((u16)(hv[1] & 0xFFFFu));
          const float h3 = bfhi(hv[1]);
          const float t0 = h0 * accT[nt][0];
          const float t1 = h1 * accT[nt][1];
          const float t2 = h2 * accT[nt][2];
          const float t3 = h3 * accT[nt][3];
          v[0] = t0 > 0.f ? t0 : (__expf(t0) - 1.0f);
          v[1] = t1 > 0.f ? t1 : (__expf(t1) - 1.0f);
          v[2] = t2 > 0.f ? t2 : (__expf(t2) - 1.0f);
          v[3] = t3 > 0.f ? t3 : (__expf(t3) - 1.0f);
          *(f32x4*)(op + nt * 16 + hi * 4) = v;  // full 64B sector per inst
        }
      }
    }

    if (!more) break;
    base = nbase;
  }
}

// ================= fallback: proven round-6 fused kernel =================
__device__ __forceinline__ void stage_w(const float* __restrict__ Wg, u16* lds, int tid) {
#pragma unroll
  for (int i = 0; i < 8; ++i) {
    const int c = tid + i * 256;
    const int n = c >> 4, k8 = c & 15;
    const bf16x8 w = cvt8(Wg + n * 128 + k8 * 8);
    const int b = (n * 256 + k8 * 16) ^ ((n & 7) << 4);
    *(bf16x8*)((char*)lds + b) = w;
  }
}
__device__ __forceinline__ void combine_store32(const f32x4 (&aH)[2][8], const f32x4 (&aZ)[2][8],
                                                u16* zw, int lo, int hi) {
#pragma unroll
  for (int mt = 0; mt < 2; ++mt)
#pragma unroll
    for (int r = 0; r < 4; ++r)
#pragma unroll
      for (int nt = 0; nt < 8; ++nt) {
        const float v = aH[mt][nt][r] * aZ[mt][nt][r];
        const float e = __expf(v) - 1.0f;
        const u16 o = f2bf(v > 0.f ? v : e);
        const int m = mt * 16 + hi * 4 + r;
        const int c = nt * 16 + lo;
        *(u16*)((char*)zw + ((m * 256) + ((c * 2) ^ ((m & 7) << 4)))) = o;
      }
}
__device__ __forceinline__ void zload32(bf16x8 (&A)[2][4], const u16* zw,
                                        int lo, int hi, int swb) {
#pragma unroll
  for (int mt = 0; mt < 2; ++mt) {
    const int mb = (mt * 16 + lo) * 256;
#pragma unroll
    for (int kk = 0; kk < 4; ++kk)
      A[mt][kk] = *(const bf16x8*)((const char*)zw + (mb + ((kk * 64 + hi * 16) ^ swb)));
  }
}
__global__ __launch_bounds__(256, 2) void edge_fused_f32out_kernel(
    const float* __restrict__ E, const u32* __restrict__ SRC,
    const float* __restrict__ X,
    const float* __restrict__ Wn, const float* __restrict__ We,
    float* __restrict__ OUT, int Ne, int N) {
  __shared__ u16 Wl[128 * 128];
  __shared__ u16 Z[4][32 * 128];
  const int tid = threadIdx.x;
  const int lane = tid & 63;
  const int wave = tid >> 6;
  const int lo = lane & 15, hi = lane >> 4;
  const int rowbase = blockIdx.x * 128 + wave * 32;
  const int swb = (lo & 7) << 4;
  bool is64 = true;
#pragma unroll
  for (int t = 1; t < 32; t += 2) is64 = is64 && (SRC[t] == 0u);
  int row[2];
  bf16x8 a[2][4], xg[2][4];
#pragma unroll
  for (int mt = 0; mt < 2; ++mt) {
    row[mt] = rowbase + mt * 16 + lo;
    const int rc = row[mt] < Ne ? row[mt] : 0;
    int s = (int)SRC[is64 ? (2 * rc) : rc];
    s = (s < 0 || s >= N) ? 0 : s;
    const float* __restrict__ p = E + (size_t)rc * 128;
    const float* __restrict__ px = X + (size_t)s * 128;
#pragma unroll
    for (int kk = 0; kk < 4; ++kk) {
      a[mt][kk] = cvt8(p + kk * 32 + hi * 8);
      xg[mt][kk] = cvt8(px + kk * 32 + hi * 8);
    }
  }
  u16* __restrict__ zw = &Z[wave][0];
  f32x4 accH[2][8], accZ[2][8];
  for (int layer = 0; layer < 3; ++layer) {
    stage_w(Wn + layer * 16384, Wl, tid);
    __syncthreads();
    gemm_pass(xg, Wl, lo, hi, swb, accH);
    __syncthreads();
    stage_w(We + layer * 16384, Wl, tid);
    __syncthreads();
    gemm_pass(a, Wl, lo, hi, swb, accZ);
    __syncthreads();
    if (layer < 2) {
      combine_store32(accH, accZ, zw, lo, hi);
      zload32(a, zw, lo, hi, swb);
    } else {
#pragma unroll
      for (int mt = 0; mt < 2; ++mt)
#pragma unroll
        for (int r = 0; r < 4; ++r) {
          const int grow = rowbase + mt * 16 + hi * 4 + r;
          if (grow < Ne) {
            float* __restrict__ o = OUT + (size_t)grow * 128;
#pragma unroll
            for (int nt = 0; nt < 8; ++nt) {
              const float v = accH[mt][nt][r] * accZ[mt][nt][r];
              const float e = __expf(v) - 1.0f;
              o[nt * 16 + lo] = (v > 0.f ? v : e);
            }
          }
        }
    }
  }
}

extern "C" void kernel_launch(void* const* d_in, const int* in_sizes, int n_in,
                              void* d_out, int out_size, void* d_ws, size_t ws_size,
                              hipStream_t stream) {
  const float* X   = (const float*)d_in[0];  // input       [N][128] f32
  const u32*   SRC = (const u32*)d_in[1];    // edge_sources[Ne] int64/int32
  const float* E   = (const float*)d_in[2];  // e           [Ne][128] f32
  const float* Wn  = (const float*)d_in[3];  // W_node      [3][128][128] f32
  const float* We  = (const float*)d_in[4];  // W_edge      [3][128][128] f32
  float* OUT = (float*)d_out;                // [Ne][128] f32

  const int N  = in_sizes[0] / 128;
  const int Ne = in_sizes[1];

  const size_t hbElems = (size_t)3 * (size_t)N * 128;
  const size_t need = (hbElems + 6 * 16384) * sizeof(u16);  // Hb + 6 swz mats
  if (ws_size >= need) {
    u16* Hb   = (u16*)d_ws;
    u16* Wswz = Hb + hbElems;  // byte offset 768*N -> 16B aligned
    cvt_wswz_kernel<<<48, 256, 0, stream>>>(Wn, We, Wswz);
    node_h_kernel<<<(N + 127) / 128, 256, 0, stream>>>(X, Wswz, Hb, N);
    edge_v19_kernel<<<256, 768, 0, stream>>>(E, SRC, Wswz + 3 * 16384, Hb, OUT, Ne, N);
  } else {
    edge_fused_f32out_kernel<<<(Ne + 127) / 128, 256, 0, stream>>>(E, SRC, X, Wn, We, OUT, Ne, N);
  }
}